// Round 1
// baseline (382.640 us; speedup 1.0000x reference)
//
#include <hip/hip_runtime.h>
#include <math.h>

#define BB 2048
#define T  200
#define H  64
#define H1 80
#define H2 40

// ws layout (floats): Wq[H*H1] | Wk[H*H1] | W2T[H2*H1]
#define WS_WQ  0
#define WS_WK  (H * H1)
#define WS_W2T (2 * H * H1)

// ---------------- prep: fold W1, transpose W2 ----------------
__global__ void prep_kernel(const float* __restrict__ W1,
                            const float* __restrict__ W2,
                            float* __restrict__ ws) {
    int i = blockIdx.x * 256 + threadIdx.x;
    if (i < H * H1) {
        int h = i / H1, f = i % H1;
        // din = [q, k, q-k, q*k]; rows of W1: [0:64)=q, [64:128)=k, [128:192)=q-k, [192:256)=q*k
        ws[WS_WQ + i] = W1[h * H1 + f] + W1[(128 + h) * H1 + f];
        ws[WS_WK + i] = W1[(64 + h) * H1 + f] - W1[(128 + h) * H1 + f];
    }
    if (i < H1 * H2) {
        int f = i / H2, g = i % H2;
        ws[WS_W2T + g * H1 + f] = W2[f * H2 + g];
    }
}

// ---------------- main: one block per batch row ----------------
__global__ __launch_bounds__(256, 2)
void din_attn_kernel(const float* __restrict__ query,
                     const float* __restrict__ keys,
                     const int*   __restrict__ keys_length,
                     const float* __restrict__ W1,   // Wp = W1 + 192*H1
                     const float* __restrict__ b1,
                     const float* __restrict__ b2,
                     const float* __restrict__ Wfc,
                     const float* __restrict__ bfc,
                     const float* __restrict__ ws,
                     float* __restrict__ out)
{
    __shared__ float sK[T * 65 + 8];   // keys padded: bank = (t + h) % 32
    __shared__ float sQh[H1];
    __shared__ float sS[256];
    __shared__ float sRed[8];
    __shared__ float sOut[4][H];

    const int b   = blockIdx.x;
    const int tid = threadIdx.x;
    const float* kb = keys + (size_t)b * T * H;
    const float* q  = query + (size_t)b * H;

    // ---- stage keys into LDS (coalesced float4 global reads, scalar padded stores)
    for (int idx = tid; idx < T * H / 4; idx += 256) {
        float4 v = reinterpret_cast<const float4*>(kb)[idx];
        int t = (idx * 4) / H, h = (idx * 4) % H;
        float* d = &sK[t * 65 + h];
        d[0] = v.x; d[1] = v.y; d[2] = v.z; d[3] = v.w;
    }
    // ---- per-b query hidden: qh[f] = b1[f] + sum_h q[h] * Wq[h][f]
    if (tid < H1) {
        float acc = b1[tid];
        #pragma unroll 8
        for (int h = 0; h < H; ++h)
            acc += q[h] * ws[WS_WQ + h * H1 + tid];   // q[h] uniform, Wq coalesced over lanes
        sQh[tid] = acc;
    }
    __syncthreads();

    // ---- MLP per timestep (thread tid owns t = tid)
    float sc = -INFINITY;
    if (tid < T) {
        float hid[H1];
        #pragma unroll
        for (int f = 0; f < H1; ++f) hid[f] = sQh[f];

        const float* Wk   = ws + WS_WK;
        const float* Wp   = W1 + 192 * H1;
        const float* krow = &sK[tid * 65];
        for (int h = 0; h < H; ++h) {
            float kv = krow[h];          // per-lane LDS read, conflict-free
            float pv = q[h] * kv;        // q[h] uniform -> s_load
            const float* wk = Wk + h * H1;
            const float* wp = Wp + h * H1;
            #pragma unroll
            for (int f = 0; f < H1; ++f)
                hid[f] += kv * wk[f] + pv * wp[f];   // weights uniform -> SGPR operand FMA
        }
        #pragma unroll
        for (int f = 0; f < H1; ++f) hid[f] = fmaxf(hid[f], 0.f);

        const float* W2T = ws + WS_W2T;
        float s = bfc[0];
        for (int g = 0; g < H2; ++g) {
            float a = b2[g];
            const float* w2 = W2T + g * H1;
            #pragma unroll
            for (int f = 0; f < H1; ++f) a += hid[f] * w2[f];
            s += fmaxf(a, 0.f) * Wfc[g];
        }
        sc = s * 0.125f;                  // / sqrt(64)
        if (tid >= keys_length[b]) sc = -INFINITY;
    }

    // ---- softmax over t (block-wide; invalid/tail threads hold -inf)
    float m = sc;
    #pragma unroll
    for (int off = 32; off > 0; off >>= 1) m = fmaxf(m, __shfl_xor(m, off));
    if ((tid & 63) == 0) sRed[tid >> 6] = m;
    __syncthreads();
    float mx = fmaxf(fmaxf(sRed[0], sRed[1]), fmaxf(sRed[2], sRed[3]));
    float e = __expf(sc - mx);            // -inf -> 0 (len >= 1 so mx finite)
    float ssum = e;
    #pragma unroll
    for (int off = 32; off > 0; off >>= 1) ssum += __shfl_xor(ssum, off);
    if ((tid & 63) == 0) sRed[4 + (tid >> 6)] = ssum;
    __syncthreads();
    float denom = sRed[4] + sRed[5] + sRed[6] + sRed[7];
    sS[tid] = e / denom;
    __syncthreads();

    // ---- output: out[b][h] = sum_t attn[t] * keys[t][h]
    int h   = tid & 63;
    int grp = tid >> 6;
    float acc = 0.f;
    for (int t = grp * 50; t < grp * 50 + 50; ++t)
        acc += sS[t] * sK[t * 65 + h];    // sS broadcast, sK 2-way (free)
    sOut[grp][h] = acc;
    __syncthreads();
    if (tid < H)
        out[(size_t)b * H + tid] = sOut[0][tid] + sOut[1][tid] + sOut[2][tid] + sOut[3][tid];
}

extern "C" void kernel_launch(void* const* d_in, const int* in_sizes, int n_in,
                              void* d_out, int out_size, void* d_ws, size_t ws_size,
                              hipStream_t stream) {
    const float* query       = (const float*)d_in[0];
    const float* keys        = (const float*)d_in[1];
    const int*   keys_length = (const int*)  d_in[2];
    const float* W1          = (const float*)d_in[3];
    const float* b1          = (const float*)d_in[4];
    const float* W2          = (const float*)d_in[5];
    const float* b2          = (const float*)d_in[6];
    const float* Wfc         = (const float*)d_in[7];
    const float* bfc         = (const float*)d_in[8];
    float* out = (float*)d_out;
    float* ws  = (float*)d_ws;

    prep_kernel<<<(H * H1 + 255) / 256, 256, 0, stream>>>(W1, W2, ws);
    din_attn_kernel<<<BB, 256, 0, stream>>>(query, keys, keys_length, W1, b1, b2,
                                            Wfc, bfc, ws, out);
}

// Round 2
// 89.105 us; speedup vs baseline: 4.2943x; 4.2943x over previous
//
#include <hip/hip_runtime.h>
#include <math.h>

#define BB 2048
#define T  200
#define H  64
#define H1 80
#define H2 40

#define MT   13          // 16-row M tiles (208 padded rows)
#define TPAD 208
#define SA_STRIDE 72     // ushort elems per sA row (144 B = 16*9 -> conflict-free frags)
#define SH_STRIDE 104    // ushort elems per sH row (208 B = 16*13)
#define SB1_STRIDE 72
#define SB2_STRIDE 104

typedef __attribute__((ext_vector_type(8))) short short8;
typedef __attribute__((ext_vector_type(4))) float floatx4;

// ws layout (float words):
#define WS_WKT 0                       // [80][64] f32: W1k - W1qk  ([f][h])
#define WS_WPT (WS_WKT + H1 * H)       // [80][64] f32: W1qk       ([f][h])
#define WS_WQ  (WS_WPT + H1 * H)       // [64][80] f32: W1q + W1qk ([h][f])
#define WS_W2T (WS_WQ + H * H1)        // [48][104] bf16 (ushort), zero-padded

__device__ __forceinline__ unsigned short f2b(float x) {
    union { float f; unsigned u; } v; v.f = x;
    unsigned r = v.u + 0x7FFF + ((v.u >> 16) & 1);   // RNE (finite inputs only)
    return (unsigned short)(r >> 16);
}
__device__ __forceinline__ float b2f(unsigned short u) {
    union { unsigned u; float f; } v; v.u = ((unsigned)u) << 16;
    return v.f;
}

// ---------------- prep: fold W1, transpose/convert W2 ----------------
__global__ void prep_kernel(const float* __restrict__ W1,
                            const float* __restrict__ W2,
                            float* __restrict__ ws) {
    int i = blockIdx.x * 256 + threadIdx.x;          // 0..5119
    if (i < H1 * H) {
        int f = i / H, h = i % H;
        // din = [q, k, q-k, q*k]; W1 rows: [0:64)q [64:128)k [128:192)q-k [192:256)q*k
        ws[WS_WKT + i] = W1[(64 + h) * H1 + f] - W1[(128 + h) * H1 + f];
        ws[WS_WPT + i] = W1[(192 + h) * H1 + f];
        ws[WS_WQ + h * H1 + f] = W1[h * H1 + f] + W1[(128 + h) * H1 + f];
    }
    if (i < 48 * SB2_STRIDE) {                       // 4992 bf16 elems
        int n = i / SB2_STRIDE, k = i % SB2_STRIDE;
        float v = (n < H2 && k < H1) ? W2[k * H2 + n] : 0.f;
        ((unsigned short*)(ws + WS_W2T))[i] = f2b(v);
    }
}

// ---------------- main: one block (512 thr) per batch row ----------------
__global__ __launch_bounds__(512)
void din_attn_kernel(const float* __restrict__ query,
                     const float* __restrict__ keys,
                     const int*   __restrict__ keys_length,
                     const float* __restrict__ b1,
                     const float* __restrict__ b2,
                     const float* __restrict__ Wfc,
                     const float* __restrict__ bfc,
                     const float* __restrict__ ws,
                     float* __restrict__ out)
{
    __shared__ unsigned short sA[TPAD * SA_STRIDE];   // bf16 keys          29952 B
    __shared__ unsigned short sH[TPAD * SH_STRIDE];   // bf16 hid1          43264 B
    __shared__ unsigned short sB1[H1 * SB1_STRIDE];   // bf16 folded W1     11520 B
    __shared__ unsigned short sB2[48 * SB2_STRIDE];   // bf16 W2^T padded    9984 B
    __shared__ float sQ[H];
    __shared__ float sQh[H1];
    __shared__ float sS[TPAD];
    __shared__ float sOut[8][H];
    __shared__ float sRed[16];

    const int b   = blockIdx.x;
    const int tid = threadIdx.x;
    const int wv  = tid >> 6, ln = tid & 63;
    const int lrow = ln & 15;            // m/n index within a 16-tile
    const int lk8  = (ln >> 4) * 8;      // k-element offset of this lane's frag

    const float* kb = keys + (size_t)b * T * H;

    // ===== phase 0: keys->bf16 LDS, zero pads, copy W2T, q, qh =====
    for (int idx = tid; idx < T * H / 4; idx += 512) {
        float4 v = reinterpret_cast<const float4*>(kb)[idx];
        int t = idx >> 4, h = (idx & 15) << 2;
        uint2 p;
        p.x = (unsigned)f2b(v.x) | ((unsigned)f2b(v.y) << 16);
        p.y = (unsigned)f2b(v.z) | ((unsigned)f2b(v.w) << 16);
        *reinterpret_cast<uint2*>(&sA[t * SA_STRIDE + h]) = p;
    }
    for (int idx = tid; idx < (TPAD * SH_STRIDE) / 8; idx += 512) {
        uint4 z; z.x = z.y = z.z = z.w = 0;
        reinterpret_cast<uint4*>(sH)[idx] = z;
    }
    for (int idx = tid; idx < 8 * SA_STRIDE / 2; idx += 512)
        reinterpret_cast<unsigned*>(&sA[200 * SA_STRIDE])[idx] = 0;  // pad rows
    for (int idx = tid; idx < (48 * SB2_STRIDE) / 8; idx += 512)
        reinterpret_cast<uint4*>(sB2)[idx] =
            reinterpret_cast<const uint4*>(ws + WS_W2T)[idx];
    if (tid < H) sQ[tid] = query[(size_t)b * H + tid];
    if (tid < H1) {
        float acc = b1[tid];
        const float* q = query + (size_t)b * H;
        #pragma unroll 8
        for (int h = 0; h < H; ++h) acc += q[h] * ws[WS_WQ + h * H1 + tid];
        sQh[tid] = acc;
    }
    __syncthreads();

    // ===== phase 1: fold q into stage-1 weights: B1[f][h] = Wk + q[h]*Wp =====
    for (int idx = tid; idx < H1 * H / 2; idx += 512) {
        int f = idx >> 5, hp = (idx & 31) << 1;
        float q0 = sQ[hp], q1 = sQ[hp + 1];
        float v0 = ws[WS_WKT + f * H + hp]     + q0 * ws[WS_WPT + f * H + hp];
        float v1 = ws[WS_WKT + f * H + hp + 1] + q1 * ws[WS_WPT + f * H + hp + 1];
        unsigned p = (unsigned)f2b(v0) | ((unsigned)f2b(v1) << 16);
        *reinterpret_cast<unsigned*>(&sB1[f * SB1_STRIDE + hp]) = p;
    }
    __syncthreads();

    // ===== phase 2: stage-1 MFMA  hid[208][80] = ReLU(A @ B1 + qh) =====
    short8 bf[5][2];
    #pragma unroll
    for (int nt = 0; nt < 5; ++nt)
        #pragma unroll
        for (int ks = 0; ks < 2; ++ks)
            bf[nt][ks] = *reinterpret_cast<const short8*>(
                &sB1[(nt * 16 + lrow) * SB1_STRIDE + ks * 32 + lk8]);

    #pragma unroll
    for (int mi = 0; mi < 2; ++mi) {
        int mt = wv + mi * 8;
        if (mt >= MT) break;
        short8 af[2];
        #pragma unroll
        for (int ks = 0; ks < 2; ++ks)
            af[ks] = *reinterpret_cast<const short8*>(
                &sA[(mt * 16 + lrow) * SA_STRIDE + ks * 32 + lk8]);
        #pragma unroll
        for (int nt = 0; nt < 5; ++nt) {
            floatx4 acc = {0.f, 0.f, 0.f, 0.f};
            acc = __builtin_amdgcn_mfma_f32_16x16x32_bf16(af[0], bf[nt][0], acc, 0, 0, 0);
            acc = __builtin_amdgcn_mfma_f32_16x16x32_bf16(af[1], bf[nt][1], acc, 0, 0, 0);
            float qh = sQh[nt * 16 + lrow];   // D: col=lane&15 (f), row=(lane>>4)*4+r (t)
            int tb = mt * 16 + (ln >> 4) * 4;
            #pragma unroll
            for (int r = 0; r < 4; ++r)
                sH[(tb + r) * SH_STRIDE + nt * 16 + lrow] = f2b(fmaxf(acc[r] + qh, 0.f));
        }
    }
    __syncthreads();

    // ===== phase 3: stage-2 MFMA + fused Wfc reduce -> raw scores =====
    short8 b2frag[3][3];
    #pragma unroll
    for (int nt = 0; nt < 3; ++nt)
        #pragma unroll
        for (int ks = 0; ks < 3; ++ks)
            b2frag[nt][ks] = *reinterpret_cast<const short8*>(
                &sB2[(nt * 16 + lrow) * SB2_STRIDE + ks * 32 + lk8]);
    float wfcv[3], b2v[3];
    #pragma unroll
    for (int nt = 0; nt < 3; ++nt) {
        int g = nt * 16 + lrow;
        wfcv[nt] = (g < H2) ? Wfc[g] : 0.f;
        b2v[nt]  = (g < H2) ? b2[g]  : 0.f;
    }
    float bfc0 = bfc[0];

    #pragma unroll
    for (int mi = 0; mi < 2; ++mi) {
        int mt = wv + mi * 8;
        if (mt >= MT) break;
        short8 a2[3];
        #pragma unroll
        for (int ks = 0; ks < 3; ++ks)
            a2[ks] = *reinterpret_cast<const short8*>(
                &sH[(mt * 16 + lrow) * SH_STRIDE + ks * 32 + lk8]);
        floatx4 vsum = {0.f, 0.f, 0.f, 0.f};
        #pragma unroll
        for (int nt = 0; nt < 3; ++nt) {
            floatx4 acc = {0.f, 0.f, 0.f, 0.f};
            #pragma unroll
            for (int ks = 0; ks < 3; ++ks)
                acc = __builtin_amdgcn_mfma_f32_16x16x32_bf16(a2[ks], b2frag[nt][ks], acc, 0, 0, 0);
            #pragma unroll
            for (int r = 0; r < 4; ++r)
                vsum[r] += fmaxf(acc[r] + b2v[nt], 0.f) * wfcv[nt];
        }
        #pragma unroll
        for (int r = 0; r < 4; ++r) {
            vsum[r] += __shfl_xor(vsum[r], 1);
            vsum[r] += __shfl_xor(vsum[r], 2);
            vsum[r] += __shfl_xor(vsum[r], 4);
            vsum[r] += __shfl_xor(vsum[r], 8);
        }
        if (lrow == 0) {
            int tb = mt * 16 + (ln >> 4) * 4;
            #pragma unroll
            for (int r = 0; r < 4; ++r)
                sS[tb + r] = (vsum[r] + bfc0) * 0.125f;
        }
    }
    __syncthreads();

    // ===== phase 4: masked softmax over t =====
    int len = keys_length[b];
    float s = -INFINITY;
    if (tid < TPAD) s = (tid < len) ? sS[tid] : -INFINITY;
    float m = s;
    #pragma unroll
    for (int off = 32; off > 0; off >>= 1) m = fmaxf(m, __shfl_xor(m, off));
    if (ln == 0) sRed[wv] = m;
    __syncthreads();
    float mx = sRed[0];
    #pragma unroll
    for (int i = 1; i < 8; ++i) mx = fmaxf(mx, sRed[i]);
    float e = (tid < TPAD) ? __expf(s - mx) : 0.f;
    float sum = e;
    #pragma unroll
    for (int off = 32; off > 0; off >>= 1) sum += __shfl_xor(sum, off);
    if (ln == 0) sRed[8 + wv] = sum;
    __syncthreads();
    float denom = sRed[8];
    #pragma unroll
    for (int i = 1; i < 8; ++i) denom += sRed[8 + i];
    float inv = 1.f / denom;
    __syncthreads();
    if (tid < TPAD) sS[tid] = e * inv;
    __syncthreads();

    // ===== phase 5: out[b][h] = sum_t attn[t] * keys[t][h] =====
    float acc = 0.f;
    for (int t = wv * 26; t < wv * 26 + 26; ++t)
        acc += sS[t] * b2f(sA[t * SA_STRIDE + ln]);
    sOut[wv][ln] = acc;
    __syncthreads();
    if (tid < H) {
        float o = 0.f;
        #pragma unroll
        for (int g = 0; g < 8; ++g) o += sOut[g][tid];
        out[(size_t)b * H + tid] = o;
    }
}

extern "C" void kernel_launch(void* const* d_in, const int* in_sizes, int n_in,
                              void* d_out, int out_size, void* d_ws, size_t ws_size,
                              hipStream_t stream) {
    const float* query       = (const float*)d_in[0];
    const float* keys        = (const float*)d_in[1];
    const int*   keys_length = (const int*)  d_in[2];
    const float* W1          = (const float*)d_in[3];
    const float* b1          = (const float*)d_in[4];
    const float* W2          = (const float*)d_in[5];
    const float* b2          = (const float*)d_in[6];
    const float* Wfc         = (const float*)d_in[7];
    const float* bfc         = (const float*)d_in[8];
    float* out = (float*)d_out;
    float* ws  = (float*)d_ws;

    prep_kernel<<<20, 256, 0, stream>>>(W1, W2, ws);
    din_attn_kernel<<<BB, 512, 0, stream>>>(query, keys, keys_length,
                                            b1, b2, Wfc, bfc, ws, out);
}

// Round 3
// 60.362 us; speedup vs baseline: 6.3391x; 1.4762x over previous
//
#include <hip/hip_runtime.h>
#include <math.h>

#define BB 2048
#define T  200
#define H  64
#define H1 80
#define H2 40

#define MT   13          // 16-row M tiles (208 padded rows)
#define TPAD 208
#define SA_STRIDE 72     // ushort/row (144 B) keys tile
#define SB1_STRIDE 72    // ushort/row folded W1
#define SW_STRIDE 104    // ushort/row per-wave hid scratch (208 B = 16*13)
#define SB2_STRIDE 104   // ushort/row W2^T in ws

typedef __attribute__((ext_vector_type(8))) short short8;
typedef __attribute__((ext_vector_type(4))) float floatx4;

// ws layout (float words):
#define WS_WKT 0                       // [80][64] f32: W1k - W1qk  ([f][h])
#define WS_WPT (WS_WKT + H1 * H)       // [80][64] f32: W1qk       ([f][h])
#define WS_WQ  (WS_WPT + H1 * H)       // [64][80] f32: W1q + W1qk ([h][f])
#define WS_W2T (WS_WQ + H * H1)        // [48][104] bf16 (ushort), zero-padded

__device__ __forceinline__ unsigned short f2b(float x) {
    union { float f; unsigned u; } v; v.f = x;
    unsigned r = v.u + 0x7FFF + ((v.u >> 16) & 1);   // RNE (finite inputs only)
    return (unsigned short)(r >> 16);
}
__device__ __forceinline__ float b2f(unsigned short u) {
    union { unsigned u; float f; } v; v.u = ((unsigned)u) << 16;
    return v.f;
}

// ---------------- prep: fold W1, transpose/convert W2 ----------------
__global__ void prep_kernel(const float* __restrict__ W1,
                            const float* __restrict__ W2,
                            float* __restrict__ ws) {
    int i = blockIdx.x * 256 + threadIdx.x;          // 0..5119
    if (i < H1 * H) {
        int f = i / H, h = i % H;
        // din = [q, k, q-k, q*k]; W1 rows: [0:64)q [64:128)k [128:192)q-k [192:256)q*k
        ws[WS_WKT + i] = W1[(64 + h) * H1 + f] - W1[(128 + h) * H1 + f];
        ws[WS_WPT + i] = W1[(192 + h) * H1 + f];
        ws[WS_WQ + h * H1 + f] = W1[h * H1 + f] + W1[(128 + h) * H1 + f];
    }
    if (i < 48 * SB2_STRIDE) {                       // 4992 bf16 elems
        int n = i / SB2_STRIDE, k = i % SB2_STRIDE;
        float v = (n < H2 && k < H1) ? W2[k * H2 + n] : 0.f;
        ((unsigned short*)(ws + WS_W2T))[i] = f2b(v);
    }
}

// ---------------- main: one block (512 thr) per batch row ----------------
__global__ __launch_bounds__(512, 4)
void din_attn_kernel(const float* __restrict__ query,
                     const float* __restrict__ keys,
                     const int*   __restrict__ keys_length,
                     const float* __restrict__ b1,
                     const float* __restrict__ b2,
                     const float* __restrict__ Wfc,
                     const float* __restrict__ bfc,
                     const float* __restrict__ ws,
                     float* __restrict__ out)
{
    __shared__ unsigned short sA[TPAD * SA_STRIDE];      // 29952 B
    __shared__ unsigned short sHw[8][16 * SW_STRIDE];    // 26624 B per-wave scratch
    __shared__ unsigned short sB1[H1 * SB1_STRIDE];      // 11520 B
    __shared__ float sQh[H1];                            //   320 B
    __shared__ float sS[TPAD];                           //   832 B
    __shared__ float sOut[8][H];                         //  2048 B
    __shared__ float sRed[16];                           //    64 B

    const int b   = blockIdx.x;
    const int tid = threadIdx.x;
    const int wv  = tid >> 6, ln = tid & 63;
    const int lrow = ln & 15;            // m/n index within a 16-tile
    const int lk8  = (ln >> 4) * 8;      // k-element offset of this lane's frag

    const float* kb = keys + (size_t)b * T * H;
    const float* qg = query + (size_t)b * H;

    // ---- hoisted global loads (latency hides under key staging) ----
    const unsigned short* w2t = (const unsigned short*)(ws + WS_W2T);
    short8 b2frag[3][3];
    #pragma unroll
    for (int nt = 0; nt < 3; ++nt)
        #pragma unroll
        for (int ks = 0; ks < 3; ++ks)
            b2frag[nt][ks] = *reinterpret_cast<const short8*>(
                &w2t[(nt * 16 + lrow) * SB2_STRIDE + ks * 32 + lk8]);
    float wfcv[3], b2v[3];
    #pragma unroll
    for (int nt = 0; nt < 3; ++nt) {
        int g = nt * 16 + lrow;
        wfcv[nt] = (g < H2) ? Wfc[g] : 0.f;
        b2v[nt]  = (g < H2) ? b2[g]  : 0.f;
    }
    float bfc0 = bfc[0];
    int len = keys_length[b];

    // ===== phase 0 (single barrier): stage keys, fold W1, qh, zero tails =====
    for (int idx = tid; idx < T * H / 4; idx += 512) {
        float4 v = reinterpret_cast<const float4*>(kb)[idx];
        int t = idx >> 4, h = (idx & 15) << 2;
        uint2 p;
        p.x = (unsigned)f2b(v.x) | ((unsigned)f2b(v.y) << 16);
        p.y = (unsigned)f2b(v.z) | ((unsigned)f2b(v.w) << 16);
        *reinterpret_cast<uint2*>(&sA[t * SA_STRIDE + h]) = p;
    }
    for (int idx = tid; idx < 8 * SA_STRIDE / 2; idx += 512)
        reinterpret_cast<unsigned*>(&sA[200 * SA_STRIDE])[idx] = 0;  // pad rows
    // fold q into stage-1 weights: B1[f][h] = Wk[f][h] + q[h]*Wp[f][h]
    for (int idx = tid; idx < H1 * H / 2; idx += 512) {
        int f = idx >> 5, hp = (idx & 31) << 1;
        float q0 = qg[hp], q1 = qg[hp + 1];
        float v0 = ws[WS_WKT + f * H + hp]     + q0 * ws[WS_WPT + f * H + hp];
        float v1 = ws[WS_WKT + f * H + hp + 1] + q1 * ws[WS_WPT + f * H + hp + 1];
        unsigned p = (unsigned)f2b(v0) | ((unsigned)f2b(v1) << 16);
        *reinterpret_cast<unsigned*>(&sB1[f * SB1_STRIDE + hp]) = p;
    }
    if (tid < H1) {
        float acc = b1[tid];
        #pragma unroll 8
        for (int h = 0; h < H; ++h) acc += qg[h] * ws[WS_WQ + h * H1 + tid];
        sQh[tid] = acc;
    }
    {   // zero own-wave scratch cols 80..95 (read by ks=2 of stage-2, never written)
        uint2 z; z.x = 0; z.y = 0;
        *reinterpret_cast<uint2*>(&sHw[wv][lrow * SW_STRIDE + 80 + (ln >> 4) * 4]) = z;
    }
    __syncthreads();

    // ===== phase 1: per-M-tile fused stage1 MFMA -> own-wave scratch -> stage2 MFMA =====
    unsigned short* hw = &sHw[wv][0];
    #pragma unroll
    for (int mi = 0; mi < 2; ++mi) {
        int mt = wv + mi * 8;
        if (mt >= MT) break;
        short8 af[2];
        #pragma unroll
        for (int ks = 0; ks < 2; ++ks)
            af[ks] = *reinterpret_cast<const short8*>(
                &sA[(mt * 16 + lrow) * SA_STRIDE + ks * 32 + lk8]);
        // stage-1: hid[16][80] = ReLU(A @ B1 + qh)
        #pragma unroll
        for (int nt = 0; nt < 5; ++nt) {
            short8 bf0 = *reinterpret_cast<const short8*>(
                &sB1[(nt * 16 + lrow) * SB1_STRIDE + lk8]);
            short8 bf1 = *reinterpret_cast<const short8*>(
                &sB1[(nt * 16 + lrow) * SB1_STRIDE + 32 + lk8]);
            floatx4 acc = {0.f, 0.f, 0.f, 0.f};
            acc = __builtin_amdgcn_mfma_f32_16x16x32_bf16(af[0], bf0, acc, 0, 0, 0);
            acc = __builtin_amdgcn_mfma_f32_16x16x32_bf16(af[1], bf1, acc, 0, 0, 0);
            float qh = sQh[nt * 16 + lrow];   // D: col=lane&15 (f), row=(lane>>4)*4+r (t)
            int rb = (ln >> 4) * 4;
            #pragma unroll
            for (int r = 0; r < 4; ++r)
                hw[(rb + r) * SW_STRIDE + nt * 16 + lrow] = f2b(fmaxf(acc[r] + qh, 0.f));
        }
        // stage-2: scores = relu(hid @ W2 + b2) . Wfc  (own scratch, no barrier)
        short8 a2[3];
        #pragma unroll
        for (int ks = 0; ks < 3; ++ks)
            a2[ks] = *reinterpret_cast<const short8*>(
                &hw[lrow * SW_STRIDE + ks * 32 + lk8]);
        floatx4 vsum = {0.f, 0.f, 0.f, 0.f};
        #pragma unroll
        for (int nt = 0; nt < 3; ++nt) {
            floatx4 acc = {0.f, 0.f, 0.f, 0.f};
            #pragma unroll
            for (int ks = 0; ks < 3; ++ks)
                acc = __builtin_amdgcn_mfma_f32_16x16x32_bf16(a2[ks], b2frag[nt][ks], acc, 0, 0, 0);
            #pragma unroll
            for (int r = 0; r < 4; ++r)
                vsum[r] += fmaxf(acc[r] + b2v[nt], 0.f) * wfcv[nt];
        }
        #pragma unroll
        for (int r = 0; r < 4; ++r) {
            vsum[r] += __shfl_xor(vsum[r], 1);
            vsum[r] += __shfl_xor(vsum[r], 2);
            vsum[r] += __shfl_xor(vsum[r], 4);
            vsum[r] += __shfl_xor(vsum[r], 8);
        }
        if (lrow == 0) {
            int tb = mt * 16 + (ln >> 4) * 4;
            #pragma unroll
            for (int r = 0; r < 4; ++r)
                sS[tb + r] = (vsum[r] + bfc0) * 0.125f;
        }
    }
    __syncthreads();

    // ===== phase 2: masked softmax over t =====
    float s = -INFINITY;
    if (tid < TPAD) s = (tid < len) ? sS[tid] : -INFINITY;
    float m = s;
    #pragma unroll
    for (int off = 32; off > 0; off >>= 1) m = fmaxf(m, __shfl_xor(m, off));
    if (ln == 0) sRed[wv] = m;
    __syncthreads();
    float mx = sRed[0];
    #pragma unroll
    for (int i = 1; i < 8; ++i) mx = fmaxf(mx, sRed[i]);
    float e = (tid < TPAD) ? __expf(s - mx) : 0.f;
    float sum = e;
    #pragma unroll
    for (int off = 32; off > 0; off >>= 1) sum += __shfl_xor(sum, off);
    if (ln == 0) sRed[8 + wv] = sum;
    __syncthreads();
    float denom = sRed[8];
    #pragma unroll
    for (int i = 1; i < 8; ++i) denom += sRed[8 + i];
    float inv = 1.f / denom;
    if (tid < TPAD) sS[tid] = e * inv;
    __syncthreads();

    // ===== phase 3: out[b][h] = sum_t attn[t] * keys[t][h] =====
    float acc = 0.f;
    for (int t = wv * 26; t < wv * 26 + 26; ++t)
        acc += sS[t] * b2f(sA[t * SA_STRIDE + ln]);
    sOut[wv][ln] = acc;
    __syncthreads();
    if (tid < H) {
        float o = 0.f;
        #pragma unroll
        for (int g = 0; g < 8; ++g) o += sOut[g][tid];
        out[(size_t)b * H + tid] = o;
    }
}

extern "C" void kernel_launch(void* const* d_in, const int* in_sizes, int n_in,
                              void* d_out, int out_size, void* d_ws, size_t ws_size,
                              hipStream_t stream) {
    const float* query       = (const float*)d_in[0];
    const float* keys        = (const float*)d_in[1];
    const int*   keys_length = (const int*)  d_in[2];
    const float* W1          = (const float*)d_in[3];
    const float* b1          = (const float*)d_in[4];
    const float* W2          = (const float*)d_in[5];
    const float* b2          = (const float*)d_in[6];
    const float* Wfc         = (const float*)d_in[7];
    const float* bfc         = (const float*)d_in[8];
    float* out = (float*)d_out;
    float* ws  = (float*)d_ws;

    prep_kernel<<<20, 256, 0, stream>>>(W1, W2, ws);
    din_attn_kernel<<<BB, 512, 0, stream>>>(query, keys, keys_length,
                                            b1, b2, Wfc, bfc, ws, out);
}